// Round 8
// baseline (280.765 us; speedup 1.0000x reference)
//
#include <hip/hip_runtime.h>
#include <hip/hip_bf16.h>

typedef unsigned short u16;
typedef __attribute__((ext_vector_type(8))) short bf16x8;
typedef __attribute__((ext_vector_type(4))) short s16x4;
typedef __attribute__((ext_vector_type(4))) float f32x4;

// Q pre-scale: 0.125 * log2(e) -> logits come out in log2 domain
#define QSCALE 0.18033688011116012f
#define RPSCALE 8.0f
#define EXP2(x) __builtin_amdgcn_exp2f(x)

__device__ __forceinline__ float bf2f(u16 u) {
  union { unsigned int i; float f; } v; v.i = ((unsigned int)u) << 16; return v.f;
}
__device__ __forceinline__ u16 f2bf(float f) {
  union { float f; unsigned int i; } v; v.f = f;
  unsigned int r = v.i + 0x7fffu + ((v.i >> 16) & 1u);
  return (u16)(r >> 16);
}
__device__ __forceinline__ unsigned int pk2bf(float a, float b) {
  union { __hip_bfloat162 h; unsigned int u; } cv;
  cv.h = __float22bfloat162_rn(float2{a, b});
  return cv.u;
}
__device__ __forceinline__ f32x4 MFMA(bf16x8 a, bf16x8 b, f32x4 c) {
  return __builtin_amdgcn_mfma_f32_16x16x32_bf16(a, b, c, 0, 0, 0);
}
__device__ __forceinline__ void cvt8(const float* p, uint4* dst) {
  float4 f0 = *(const float4*)(p);
  float4 f1 = *(const float4*)(p + 4);
  u16* t = (u16*)dst;
  t[0] = f2bf(f0.x); t[1] = f2bf(f0.y); t[2] = f2bf(f0.z); t[3] = f2bf(f0.w);
  t[4] = f2bf(f1.x); t[5] = f2bf(f1.y); t[6] = f2bf(f1.z); t[7] = f2bf(f1.w);
}
__device__ __forceinline__ void cvt8s(const float* p, uint4* dst, float s) {
  float4 f0 = *(const float4*)(p);
  float4 f1 = *(const float4*)(p + 4);
  u16* t = (u16*)dst;
  t[0] = f2bf(f0.x * s); t[1] = f2bf(f0.y * s); t[2] = f2bf(f0.z * s); t[3] = f2bf(f0.w * s);
  t[4] = f2bf(f1.x * s); t[5] = f2bf(f1.y * s); t[6] = f2bf(f1.z * s); t[7] = f2bf(f1.w * s);
}
// async global->LDS, 16B per lane; LDS dest = wave-uniform base + lane*16
__device__ __forceinline__ void gld16(const u16* g, u16* l) {
  __builtin_amdgcn_global_load_lds(
      (const __attribute__((address_space(1))) unsigned int*)g,
      (__attribute__((address_space(3))) unsigned int*)l, 16, 0, 0);
}

// ---------------------------------------------------------------------------
// One-shot fp32 -> bf16 cast of x, qkv_w, proj_w (grid covers all three).
// ---------------------------------------------------------------------------
#define N8_X  786432   // 8*32*32*768 / 8
#define N8_QW 221184   // 2304*768 / 8
#define N8_PW 73728    // 768*768 / 8
__global__ __launch_bounds__(256) void cast_kernel(
    const float* __restrict__ x, const float* __restrict__ qw, const float* __restrict__ pw,
    u16* __restrict__ xb, u16* __restrict__ qwb, u16* __restrict__ pwb)
{
  const int i = blockIdx.x * 256 + threadIdx.x;
  const float* s; u16* d; int off;
  if (i < N8_X)            { s = x;  d = xb;  off = i; }
  else if (i < N8_X+N8_QW) { s = qw; d = qwb; off = i - N8_X; }
  else                     { s = pw; d = pwb; off = i - (N8_X + N8_QW); }
  uint4 pk; cvt8(s + (size_t)off * 8, &pk);
  *(uint4*)(d + (size_t)off * 8) = pk;
}

// ---------------------------------------------------------------------------
// GEMM: C = A @ Bw^T + bias.  A: MxK row-major bf16, Bw: NxK row-major bf16,
// bias fp32.  Staging via global_load_lds (16B/lane).  XCD-swizzled grid.
// MODE 0: plain row-major fp32 C0[m*N+n]
// MODE 1: QKV scatter: n -> (which, head, c); m -> (b, npos)
//   which 0 -> Q[bh][npos][c] bf16, PRE-SCALED by QSCALE
//   which 1 -> K fragment-linear: [bh][kt][mk][half][lane][8]
//   which 2 -> V fragment-linear: [bh][kt][ks][nd][lane][8]
// ---------------------------------------------------------------------------
template<int MODE, int NXB>
__global__ __launch_bounds__(256) void gemm_bt(
    const u16* __restrict__ A, const u16* __restrict__ Bw, const float* __restrict__ bias,
    void* __restrict__ C0v, u16* __restrict__ C1, u16* __restrict__ C2,
    int M, int N, int K)
{
  __shared__ u16 sA[128 * 32];   // [row][k] 64 B rows, written by DMA in lane order
  __shared__ u16 sB[128 * 32];
  const int tid = threadIdx.x;
  const int lane = tid & 63, wv = tid >> 6;
  const int wr = wv >> 1, wc = wv & 1;
  const int l16 = lane & 15, quad = lane >> 4;
  // XCD swizzle: my ≡ bi (mod 8)
  const int bi = blockIdx.x;
  const int t = bi >> 3;
  const int nx = t % NXB;
  const int my = ((t / NXB) << 3) | (bi & 7);
  const int m0 = my << 7, n0 = nx << 7;

  const int srow = tid >> 2, scol = (tid & 3) << 3;
  const u16* gA0 = A  + (size_t)(m0 + srow) * K + scol;
  const u16* gB0 = Bw + (size_t)(n0 + srow) * K + scol;
  const u16* gA1 = gA0 + (size_t)64 * K;
  const u16* gB1 = gB0 + (size_t)64 * K;
  u16* const lwA0 = sA + wv * 512;
  u16* const lwA1 = sA + 2048 + wv * 512;
  u16* const lwB0 = sB + wv * 512;
  u16* const lwB1 = sB + 2048 + wv * 512;

  f32x4 acc[4][4];
  #pragma unroll
  for (int i = 0; i < 4; ++i)
    #pragma unroll
    for (int j = 0; j < 4; ++j) {
      acc[i][j][0] = 0.f; acc[i][j][1] = 0.f; acc[i][j][2] = 0.f; acc[i][j][3] = 0.f;
    }

  for (int k0 = 0; k0 < K; k0 += 32) {
    __syncthreads();
    gld16(gA0 + k0, lwA0);
    gld16(gA1 + k0, lwA1);
    gld16(gB0 + k0, lwB0);
    gld16(gB1 + k0, lwB1);
    __syncthreads();
    bf16x8 af[4], bfr[4];
    #pragma unroll
    for (int i = 0; i < 4; ++i)
      af[i] = *(const bf16x8*)(sA + (wr * 64 + i * 16 + l16) * 32 + quad * 8);
    #pragma unroll
    for (int j = 0; j < 4; ++j)
      bfr[j] = *(const bf16x8*)(sB + (wc * 64 + j * 16 + l16) * 32 + quad * 8);
    #pragma unroll
    for (int i = 0; i < 4; ++i)
      #pragma unroll
      for (int j = 0; j < 4; ++j)
        acc[i][j] = MFMA(af[i], bfr[j], acc[i][j]);
  }

  #pragma unroll
  for (int j = 0; j < 4; ++j) {
    const int n = n0 + wc * 64 + j * 16 + l16;
    const float bv = bias[n];
    if (MODE == 0) {
      float* C0 = (float*)C0v;
      #pragma unroll
      for (int i = 0; i < 4; ++i) {
        const int m = m0 + wr * 64 + i * 16 + quad * 4;
        #pragma unroll
        for (int r = 0; r < 4; ++r)
          C0[(size_t)(m + r) * N + n] = acc[i][j][r] + bv;
      }
    } else {
      u16* C0 = (u16*)C0v;
      const int which = n / 768;            // uniform per 16-lane span
      const int rem = n - which * 768;
      const int head = rem >> 6, c = rem & 63;
      #pragma unroll
      for (int i = 0; i < 4; ++i) {
        const int m = m0 + wr * 64 + i * 16 + quad * 4;
        const int b = m >> 10, npos = m & 1023;
        const size_t bh = (size_t)(b * 12 + head);
        if (which == 0) {
          #pragma unroll
          for (int r = 0; r < 4; ++r)
            C0[(bh << 16) + ((size_t)(npos + r) << 6) + c] =
                f2bf((acc[i][j][r] + bv) * QSCALE);
        } else if (which == 1) {
          const size_t base = ((bh * 16 + (size_t)(npos >> 6)) << 12)
                            + (size_t)((((npos >> 4) & 3) * 2 + (c >> 5)) << 9)
                            + (size_t)((((npos & 15) + 16 * ((c >> 3) & 3)) << 3) + (c & 7));
          #pragma unroll
          for (int r = 0; r < 4; ++r)
            C1[base + r * 8] = f2bf(acc[i][j][r] + bv);
        } else {
          const size_t base = ((bh * 16 + (size_t)(npos >> 6)) << 12)
                            + (size_t)(((((npos >> 5) & 1) * 4 + (c >> 4))) << 9)
                            + (size_t)((((c & 15) + 16 * ((npos >> 3) & 3)) << 3) + (npos & 7));
          s16x4 pk;
          #pragma unroll
          for (int r = 0; r < 4; ++r) pk[r] = (short)f2bf(acc[i][j][r] + bv);
          *(s16x4*)(C2 + base) = pk;   // npos&7 in {0,4} -> 8B aligned
        }
      }
    }
  }
}

// ---------------------------------------------------------------------------
// Attention, barrier-free main loop, fragment-linear K/V (coalesced 16B/lane
// loads, addresses = base + kt*4096 + imm).  Q pre-scaled by 0.125*log2e,
// rel-pos scaled by 8 -> logit = add3, exp = v_exp_f32 (exp2 builtin).
// P double-buffered in LDS, kt unrolled by 2 for cross-iteration overlap.
// PV computes O^T = V^T·P^T so the epilogue is lane-local (q = l16).
// ---------------------------------------------------------------------------
__global__ __launch_bounds__(256) void attn_kernel(
    const u16* __restrict__ Q, const u16* __restrict__ Kf, const u16* __restrict__ Vf,
    const float* __restrict__ rph, const float* __restrict__ rpw,
    u16* __restrict__ Oa)
{
  // uni: prologue rp staging (9144 u16) / Sw scratch; main loop: 2x P buffers
  // (2 x 4 waves x 2304).  sSh: 4 waves x 32 x 36.  Total ~45 KB.
  __shared__ __align__(16) u16 uni[18432];
  __shared__ u16 sSh[4 * 32 * 36];

  u16* const uRPH = uni;            // 63 rows x stride 72
  u16* const uRPW = uni + 4536;     // 64 rows x stride 72 (row 63 zero)

  const int tid = threadIdx.x;
  const int wave = tid >> 6, lane = tid & 63;
  const int l16 = lane & 15, quad = lane >> 4;
  // XCD swizzle: bh ≡ blockIdx (mod 8) -> all 8 q-tiles of bh on one XCD
  const int bi = blockIdx.x;
  const int bh = (bi & 7) | ((bi >> 6) << 3);
  const int qt = (bi >> 3) & 7;
  const int qrow0 = (qt << 7) + (wave << 5);
  const int qh = qrow0 >> 5;

  u16* const pwA = uni + wave * 2304;
  u16* const pwB = uni + 9216 + wave * 2304;
  u16* const uSw = pwA;             // prologue scratch aliases P buffer A
  u16* const sShw = sSh + wave * 1152;

  bf16x8 qf[2][2];
  #pragma unroll
  for (int nq = 0; nq < 2; ++nq) {
    const u16* qp = Q + (((size_t)bh << 10) + qrow0 + nq * 16 + l16) * 64 + quad * 8;
    qf[nq][0] = *(const bf16x8*)(qp);
    qf[nq][1] = *(const bf16x8*)(qp + 32);
  }

  for (int j = tid; j < 64 * 8; j += 256) {
    const int row = j >> 3, ck = (j & 7) << 3;
    uint4 vw;
    if (row < 63) cvt8s(rpw + (size_t)row * 64 + ck, &vw, RPSCALE);
    else { vw.x = 0u; vw.y = 0u; vw.z = 0u; vw.w = 0u; }
    *(uint4*)(uRPW + row * 72 + ck) = vw;
    if (row < 63) {
      uint4 vh;
      cvt8s(rph + (size_t)row * 64 + ck, &vh, RPSCALE);
      *(uint4*)(uRPH + row * 72 + ck) = vh;
    }
  }
  __syncthreads();

  // Sh[q][kh] = Qs·rp8[qh+31-kh] -> sSh (log2 domain)
  #pragma unroll
  for (int tk = 0; tk < 2; ++tk) {
    const int kh = tk * 16 + l16;
    const u16* bp = uRPH + (qh + 31 - kh) * 72 + quad * 8;
    bf16x8 b0 = *(const bf16x8*)(bp);
    bf16x8 b1 = *(const bf16x8*)(bp + 32);
    #pragma unroll
    for (int nq = 0; nq < 2; ++nq) {
      f32x4 c; c[0] = 0.f; c[1] = 0.f; c[2] = 0.f; c[3] = 0.f;
      c = MFMA(qf[nq][0], b0, c);
      c = MFMA(qf[nq][1], b1, c);
      #pragma unroll
      for (int r = 0; r < 4; ++r)
        sShw[(nq * 16 + quad * 4 + r) * 36 + tk * 16 + l16] = f2bf(c[r]);
    }
  }

  // Sw[q][j] = Qs·rp8w[j]; held in regs until barrier
  f32x4 swc[2][4];
  #pragma unroll
  for (int tj = 0; tj < 4; ++tj) {
    const u16* bp = uRPW + (tj * 16 + l16) * 72 + quad * 8;
    bf16x8 b0 = *(const bf16x8*)(bp);
    bf16x8 b1 = *(const bf16x8*)(bp + 32);
    #pragma unroll
    for (int nq = 0; nq < 2; ++nq) {
      f32x4 c; c[0] = 0.f; c[1] = 0.f; c[2] = 0.f; c[3] = 0.f;
      c = MFMA(qf[nq][0], b0, c);
      c = MFMA(qf[nq][1], b1, c);
      swc[nq][tj] = c;
    }
  }
  __syncthreads();   // all uRPH/uRPW reads complete before uSw overwrites

  #pragma unroll
  for (int tj = 0; tj < 4; ++tj)
    #pragma unroll
    for (int nq = 0; nq < 2; ++nq)
      #pragma unroll
      for (int r = 0; r < 4; ++r)
        uSw[(nq * 16 + quad * 4 + r) * 72 + tj * 16 + l16] = f2bf(swc[nq][tj][r]);

  // gather rel_w[q][kw] = Sw[q][q-kw+31] (wave-private, in-order RAW)
  float rw[2][2][4];
  #pragma unroll
  for (int nq = 0; nq < 2; ++nq) {
    const int q = nq * 16 + l16;
    #pragma unroll
    for (int hi = 0; hi < 2; ++hi)
      #pragma unroll
      for (int r = 0; r < 4; ++r) {
        const int kw = hi * 16 + quad * 4 + r;
        rw[nq][hi][r] = bf2f(uSw[q * 72 + (q - kw + 31)]);
      }
  }

  f32x4 oacc[2][4];
  #pragma unroll
  for (int nq = 0; nq < 2; ++nq)
    #pragma unroll
    for (int nd = 0; nd < 4; ++nd) {
      oacc[nq][nd][0] = 0.f; oacc[nq][nd][1] = 0.f; oacc[nq][nd][2] = 0.f; oacc[nq][nd][3] = 0.f;
    }
  float lsum[2] = {0.f, 0.f};

  const u16* const Kfb = Kf + (((size_t)bh) << 16) + lane * 8;
  const u16* const Vfb = Vf + (((size_t)bh) << 16) + lane * 8;

  auto attn_iter = [&](int ktx, u16* pwb) {
    const u16* Kp = Kfb + ((size_t)ktx << 12);
    const u16* Vp = Vfb + ((size_t)ktx << 12);
    float rh[2][2];
    #pragma unroll
    for (int nq = 0; nq < 2; ++nq) {
      const unsigned int w2 =
          *(const unsigned int*)(sShw + (nq * 16 + l16) * 36 + (ktx << 1));
      rh[nq][0] = bf2f((u16)(w2 & 0xffffu));
      rh[nq][1] = bf2f((u16)(w2 >> 16));
    }
    // S^T = K·Qs^T  (A = K frags, coalesced; B = Q regs)
    f32x4 sacc[4][2];
    #pragma unroll
    for (int mk = 0; mk < 4; ++mk) {
      bf16x8 kf0 = *(const bf16x8*)(Kp + ((mk * 2 + 0) << 9));
      bf16x8 kf1 = *(const bf16x8*)(Kp + ((mk * 2 + 1) << 9));
      #pragma unroll
      for (int nq = 0; nq < 2; ++nq) {
        f32x4 t4; t4[0] = 0.f; t4[1] = 0.f; t4[2] = 0.f; t4[3] = 0.f;
        t4 = MFMA(kf0, qf[nq][0], t4);
        t4 = MFMA(kf1, qf[nq][1], t4);
        sacc[mk][nq] = t4;
      }
    }
    // logit = add3 (log2 domain), exp2, pack pairs, store P
    #pragma unroll
    for (int nq = 0; nq < 2; ++nq) {
      #pragma unroll
      for (int mk = 0; mk < 4; ++mk) {
        const float rhv = rh[nq][mk >> 1];
        const float* rwp = rw[nq][mk & 1];
        float e0 = EXP2(sacc[mk][nq][0] + rhv + rwp[0]);
        float e1 = EXP2(sacc[mk][nq][1] + rhv + rwp[1]);
        float e2 = EXP2(sacc[mk][nq][2] + rhv + rwp[2]);
        float e3 = EXP2(sacc[mk][nq][3] + rhv + rwp[3]);
        lsum[nq] += (e0 + e1) + (e2 + e3);
        uint2 pk2; pk2.x = pk2bf(e0, e1); pk2.y = pk2bf(e2, e3);
        *(uint2*)(pwb + (nq * 16 + l16) * 72 + mk * 16 + quad * 4) = pk2;
      }
    }
    // O^T += V^T·P^T  (A = V frags, coalesced; B = P from LDS)
    #pragma unroll
    for (int ks = 0; ks < 2; ++ks) {
      bf16x8 ap0 = *(const bf16x8*)(pwb + (l16) * 72 + ks * 32 + quad * 8);
      bf16x8 ap1 = *(const bf16x8*)(pwb + (16 + l16) * 72 + ks * 32 + quad * 8);
      #pragma unroll
      for (int nd = 0; nd < 4; ++nd) {
        bf16x8 bv = *(const bf16x8*)(Vp + ((ks * 4 + nd) << 9));
        oacc[0][nd] = MFMA(bv, ap0, oacc[0][nd]);
        oacc[1][nd] = MFMA(bv, ap1, oacc[1][nd]);
      }
    }
  };

  for (int kt = 0; kt < 16; kt += 2) {
    attn_iter(kt, pwA);
    attn_iter(kt + 1, pwB);
  }

  // softmax denominators: lane's column q = nq*16+l16; fold quads
  #pragma unroll
  for (int nq = 0; nq < 2; ++nq) {
    lsum[nq] += __shfl_xor(lsum[nq], 16);
    lsum[nq] += __shfl_xor(lsum[nq], 32);
  }

  const int b = bh / 12, head = bh - b * 12;
  #pragma unroll
  for (int nq = 0; nq < 2; ++nq) {
    const float linv = 1.0f / lsum[nq];
    const size_t base =
        ((size_t)(b << 10) + qrow0 + nq * 16 + l16) * 768 + head * 64 + quad * 4;
    #pragma unroll
    for (int nd = 0; nd < 4; ++nd) {
      s16x4 pk;
      #pragma unroll
      for (int r = 0; r < 4; ++r) pk[r] = (short)f2bf(oacc[nq][nd][r] * linv);
      *(s16x4*)(Oa + base + nd * 16) = pk;
    }
  }
}

// ---------------------------------------------------------------------------
extern "C" void kernel_launch(void* const* d_in, const int* in_sizes, int n_in,
                              void* d_out, int out_size, void* d_ws, size_t ws_size,
                              hipStream_t stream) {
  (void)in_sizes; (void)n_in; (void)out_size; (void)ws_size;
  const float* x      = (const float*)d_in[0];   // (8,32,32,768)
  const float* qkv_w  = (const float*)d_in[1];   // (2304,768)
  const float* qkv_b  = (const float*)d_in[2];   // (2304)
  const float* proj_w = (const float*)d_in[3];   // (768,768)
  const float* proj_b = (const float*)d_in[4];   // (768)
  const float* rph    = (const float*)d_in[5];   // (63,64)
  const float* rpw    = (const float*)d_in[6];   // (63,64)
  float* out = (float*)d_out;

  char* ws = (char*)d_ws;
  const size_t SZ = (size_t)96 * 1024 * 64;     // elems per plane (12 MB)
  u16* Qw  = (u16*)ws;                          // Qs [bh][n][c] bf16 (pre-scaled)
  u16* Kfw = Qw + SZ;                           // K  fragment-linear bf16
  u16* Vfw = Kfw + SZ;                          // V  fragment-linear bf16
  u16* Xb  = Vfw + SZ;                          // bf16 x; aliased as Oa after QKV GEMM
  u16* Oa  = Xb;                                //   (x dead once QKV GEMM completes)
  u16* QWb = Xb + SZ;                           // bf16 qkv_w (2304x768)
  u16* PWb = QWb + (size_t)2304 * 768;          // bf16 proj_w (768x768)  -> ~55 MB total

  cast_kernel<<<4224, 256, 0, stream>>>(x, qkv_w, proj_w, Xb, QWb, PWb);
  gemm_bt<1, 18><<<1152, 256, 0, stream>>>(Xb, QWb, qkv_b, Qw, Kfw, Vfw, 8192, 2304, 768);
  attn_kernel<<<768, 256, 0, stream>>>(Qw, Kfw, Vfw, rph, rpw, Oa);
  gemm_bt<0, 6><<<384, 256, 0, stream>>>(Oa, PWb, proj_b, out, nullptr, nullptr, 8192, 768, 768);
}

// Round 9
// 222.415 us; speedup vs baseline: 1.2623x; 1.2623x over previous
//
#include <hip/hip_runtime.h>
#include <hip/hip_bf16.h>

typedef unsigned short u16;
typedef __attribute__((ext_vector_type(8))) short bf16x8;
typedef __attribute__((ext_vector_type(4))) short s16x4;
typedef __attribute__((ext_vector_type(4))) float f32x4;

// Q pre-scale: 0.125 * log2(e) -> logits come out in log2 domain
#define QSCALE 0.18033688011116012f
#define RPSCALE 8.0f
#define EXP2(x) __builtin_amdgcn_exp2f(x)

__device__ __forceinline__ float bf2f(u16 u) {
  union { unsigned int i; float f; } v; v.i = ((unsigned int)u) << 16; return v.f;
}
__device__ __forceinline__ u16 f2bf(float f) {
  union { float f; unsigned int i; } v; v.f = f;
  unsigned int r = v.i + 0x7fffu + ((v.i >> 16) & 1u);
  return (u16)(r >> 16);
}
__device__ __forceinline__ unsigned int pk2bf(float a, float b) {
  union { __hip_bfloat162 h; unsigned int u; } cv;
  cv.h = __float22bfloat162_rn(float2{a, b});
  return cv.u;
}
__device__ __forceinline__ f32x4 MFMA(bf16x8 a, bf16x8 b, f32x4 c) {
  return __builtin_amdgcn_mfma_f32_16x16x32_bf16(a, b, c, 0, 0, 0);
}
__device__ __forceinline__ void cvt8(const float* p, uint4* dst) {
  float4 f0 = *(const float4*)(p);
  float4 f1 = *(const float4*)(p + 4);
  u16* t = (u16*)dst;
  t[0] = f2bf(f0.x); t[1] = f2bf(f0.y); t[2] = f2bf(f0.z); t[3] = f2bf(f0.w);
  t[4] = f2bf(f1.x); t[5] = f2bf(f1.y); t[6] = f2bf(f1.z); t[7] = f2bf(f1.w);
}
__device__ __forceinline__ void cvt8s(const float* p, uint4* dst, float s) {
  float4 f0 = *(const float4*)(p);
  float4 f1 = *(const float4*)(p + 4);
  u16* t = (u16*)dst;
  t[0] = f2bf(f0.x * s); t[1] = f2bf(f0.y * s); t[2] = f2bf(f0.z * s); t[3] = f2bf(f0.w * s);
  t[4] = f2bf(f1.x * s); t[5] = f2bf(f1.y * s); t[6] = f2bf(f1.z * s); t[7] = f2bf(f1.w * s);
}
// async global->LDS, 16B per lane; LDS dest = wave-uniform base + lane*16
__device__ __forceinline__ void gld16(const u16* g, u16* l) {
  __builtin_amdgcn_global_load_lds(
      (const __attribute__((address_space(1))) unsigned int*)g,
      (__attribute__((address_space(3))) unsigned int*)l, 16, 0, 0);
}

// ---------------------------------------------------------------------------
// One-shot fp32 -> bf16 cast of x, qkv_w, proj_w (grid covers all three).
// ---------------------------------------------------------------------------
#define N8_X  786432   // 8*32*32*768 / 8
#define N8_QW 221184   // 2304*768 / 8
#define N8_PW 73728    // 768*768 / 8
__global__ __launch_bounds__(256) void cast_kernel(
    const float* __restrict__ x, const float* __restrict__ qw, const float* __restrict__ pw,
    u16* __restrict__ xb, u16* __restrict__ qwb, u16* __restrict__ pwb)
{
  const int i = blockIdx.x * 256 + threadIdx.x;
  const float* s; u16* d; int off;
  if (i < N8_X)            { s = x;  d = xb;  off = i; }
  else if (i < N8_X+N8_QW) { s = qw; d = qwb; off = i - N8_X; }
  else                     { s = pw; d = pwb; off = i - (N8_X + N8_QW); }
  uint4 pk; cvt8(s + (size_t)off * 8, &pk);
  *(uint4*)(d + (size_t)off * 8) = pk;
}

// ---------------------------------------------------------------------------
// GEMM: C = A @ Bw^T + bias.  A: MxK row-major bf16, Bw: NxK row-major bf16,
// bias fp32.  Staging via global_load_lds (16B/lane).  XCD-swizzled grid.
// MODE 0: plain row-major fp32 C0[m*N+n]
// MODE 1: QKV scatter: n -> (which, head, c); m -> (b, npos)
//   which 0 -> Q[bh][npos][c] bf16, PRE-SCALED by QSCALE
//   which 1 -> K fragment-linear: [bh][kt][mk][half][lane][8]
//   which 2 -> V fragment-linear: [bh][kt][ks][nd][lane][8]
// ---------------------------------------------------------------------------
template<int MODE, int NXB>
__global__ __launch_bounds__(256) void gemm_bt(
    const u16* __restrict__ A, const u16* __restrict__ Bw, const float* __restrict__ bias,
    void* __restrict__ C0v, u16* __restrict__ C1, u16* __restrict__ C2,
    int M, int N, int K)
{
  __shared__ u16 sA[128 * 32];   // [row][k] 64 B rows, written by DMA in lane order
  __shared__ u16 sB[128 * 32];
  const int tid = threadIdx.x;
  const int lane = tid & 63, wv = tid >> 6;
  const int wr = wv >> 1, wc = wv & 1;
  const int l16 = lane & 15, quad = lane >> 4;
  // XCD swizzle: my ≡ bi (mod 8)
  const int bi = blockIdx.x;
  const int t = bi >> 3;
  const int nx = t % NXB;
  const int my = ((t / NXB) << 3) | (bi & 7);
  const int m0 = my << 7, n0 = nx << 7;

  const int srow = tid >> 2, scol = (tid & 3) << 3;
  const u16* gA0 = A  + (size_t)(m0 + srow) * K + scol;
  const u16* gB0 = Bw + (size_t)(n0 + srow) * K + scol;
  const u16* gA1 = gA0 + (size_t)64 * K;
  const u16* gB1 = gB0 + (size_t)64 * K;
  u16* const lwA0 = sA + wv * 512;
  u16* const lwA1 = sA + 2048 + wv * 512;
  u16* const lwB0 = sB + wv * 512;
  u16* const lwB1 = sB + 2048 + wv * 512;

  f32x4 acc[4][4];
  #pragma unroll
  for (int i = 0; i < 4; ++i)
    #pragma unroll
    for (int j = 0; j < 4; ++j) {
      acc[i][j][0] = 0.f; acc[i][j][1] = 0.f; acc[i][j][2] = 0.f; acc[i][j][3] = 0.f;
    }

  for (int k0 = 0; k0 < K; k0 += 32) {
    __syncthreads();
    gld16(gA0 + k0, lwA0);
    gld16(gA1 + k0, lwA1);
    gld16(gB0 + k0, lwB0);
    gld16(gB1 + k0, lwB1);
    __syncthreads();
    bf16x8 af[4], bfr[4];
    #pragma unroll
    for (int i = 0; i < 4; ++i)
      af[i] = *(const bf16x8*)(sA + (wr * 64 + i * 16 + l16) * 32 + quad * 8);
    #pragma unroll
    for (int j = 0; j < 4; ++j)
      bfr[j] = *(const bf16x8*)(sB + (wc * 64 + j * 16 + l16) * 32 + quad * 8);
    #pragma unroll
    for (int i = 0; i < 4; ++i)
      #pragma unroll
      for (int j = 0; j < 4; ++j)
        acc[i][j] = MFMA(af[i], bfr[j], acc[i][j]);
  }

  #pragma unroll
  for (int j = 0; j < 4; ++j) {
    const int n = n0 + wc * 64 + j * 16 + l16;
    const float bv = bias[n];
    if (MODE == 0) {
      float* C0 = (float*)C0v;
      #pragma unroll
      for (int i = 0; i < 4; ++i) {
        const int m = m0 + wr * 64 + i * 16 + quad * 4;
        #pragma unroll
        for (int r = 0; r < 4; ++r)
          C0[(size_t)(m + r) * N + n] = acc[i][j][r] + bv;
      }
    } else {
      u16* C0 = (u16*)C0v;
      const int which = n / 768;            // uniform per 16-lane span
      const int rem = n - which * 768;
      const int head = rem >> 6, c = rem & 63;
      #pragma unroll
      for (int i = 0; i < 4; ++i) {
        const int m = m0 + wr * 64 + i * 16 + quad * 4;
        const int b = m >> 10, npos = m & 1023;
        const size_t bh = (size_t)(b * 12 + head);
        if (which == 0) {
          #pragma unroll
          for (int r = 0; r < 4; ++r)
            C0[(bh << 16) + ((size_t)(npos + r) << 6) + c] =
                f2bf((acc[i][j][r] + bv) * QSCALE);
        } else if (which == 1) {
          const size_t base = ((bh * 16 + (size_t)(npos >> 6)) << 12)
                            + (size_t)((((npos >> 4) & 3) * 2 + (c >> 5)) << 9)
                            + (size_t)((((npos & 15) + 16 * ((c >> 3) & 3)) << 3) + (c & 7));
          #pragma unroll
          for (int r = 0; r < 4; ++r)
            C1[base + r * 8] = f2bf(acc[i][j][r] + bv);
        } else {
          const size_t base = ((bh * 16 + (size_t)(npos >> 6)) << 12)
                            + (size_t)(((((npos >> 5) & 1) * 4 + (c >> 4))) << 9)
                            + (size_t)((((c & 15) + 16 * ((npos >> 3) & 3)) << 3) + (npos & 7));
          s16x4 pk;
          #pragma unroll
          for (int r = 0; r < 4; ++r) pk[r] = (short)f2bf(acc[i][j][r] + bv);
          *(s16x4*)(C2 + base) = pk;   // npos&7 in {0,4} -> 8B aligned
        }
      }
    }
  }
}

// ---------------------------------------------------------------------------
// Attention, TLP-oriented: 64 q-rows per block (16 per wave), grid 96x16 =
// 1536 blocks -> 6 blocks/CU, 24 waves/CU.  Barrier-free main loop,
// fragment-linear K/V (coalesced, L2-hot via XCD swizzle), log2-domain
// softmax (Q pre-scaled, v_exp_f32), single wave-private P buffer,
// O^T = V^T·P^T epilogue (lane-local q).
// ---------------------------------------------------------------------------
__global__ __launch_bounds__(256) void attn_kernel(
    const u16* __restrict__ Q, const u16* __restrict__ Kf, const u16* __restrict__ Vf,
    const float* __restrict__ rph, const float* __restrict__ rpw,
    u16* __restrict__ Oa)
{
  // uni: prologue rp staging (9144 u16); main loop: 4 waves x 1152 P slices
  // (4608 u16, aliased).  sSh: 4 waves x 16 x 36 = 2304 u16.  ~23 KB total.
  __shared__ __align__(16) u16 uni[9216];
  __shared__ u16 sSh[4 * 16 * 36];

  u16* const uRPH = uni;            // 63 rows x stride 72
  u16* const uRPW = uni + 4536;     // 64 rows x stride 72 (row 63 zero)

  const int tid = threadIdx.x;
  const int wave = tid >> 6, lane = tid & 63;
  const int l16 = lane & 15, quad = lane >> 4;
  // swizzle: bh ≡ bi (mod 8) -> all 16 q-blocks of bh on one XCD
  const int bi = blockIdx.x;
  const int t = bi >> 3;
  const int qb = t & 15;                         // q-block 0..15 (64 rows each)
  const int bh = ((t >> 4) << 3) | (bi & 7);     // 0..95
  const int qrow0 = (qb << 6) + (wave << 4);     // this wave's 16 q rows
  const int qh = qrow0 >> 5;                     // wave-uniform (16 | qrow0)
  const int qwb = qrow0 & 31;                    // qw base: 0 or 16

  u16* const pw = uni + wave * 1152;   // wave-private P / Sw scratch (16 x 72)
  u16* const sShw = sSh + wave * 576;  // wave-private Sh (16 x 36)

  bf16x8 qf[2];
  {
    const u16* qp = Q + (((size_t)bh << 10) + qrow0 + l16) * 64 + quad * 8;
    qf[0] = *(const bf16x8*)(qp);
    qf[1] = *(const bf16x8*)(qp + 32);
  }

  // ---- stage rel-pos tables (fp32 -> bf16, x8 scale, log2 domain) ----
  for (int j = tid; j < 64 * 8; j += 256) {
    const int row = j >> 3, ck = (j & 7) << 3;
    uint4 vw;
    if (row < 63) cvt8s(rpw + (size_t)row * 64 + ck, &vw, RPSCALE);
    else { vw.x = 0u; vw.y = 0u; vw.z = 0u; vw.w = 0u; }
    *(uint4*)(uRPW + row * 72 + ck) = vw;
    if (row < 63) {
      uint4 vh;
      cvt8s(rph + (size_t)row * 64 + ck, &vh, RPSCALE);
      *(uint4*)(uRPH + row * 72 + ck) = vh;
    }
  }
  __syncthreads();

  // ---- Sh[q][kh] = Qs·rp8h[qh+31-kh] -> sShw (16 x 36) ----
  #pragma unroll
  for (int tk = 0; tk < 2; ++tk) {
    const int kh = tk * 16 + l16;
    const u16* bp = uRPH + (qh + 31 - kh) * 72 + quad * 8;
    bf16x8 b0 = *(const bf16x8*)(bp);
    bf16x8 b1 = *(const bf16x8*)(bp + 32);
    f32x4 c; c[0] = 0.f; c[1] = 0.f; c[2] = 0.f; c[3] = 0.f;
    c = MFMA(qf[0], b0, c);
    c = MFMA(qf[1], b1, c);
    #pragma unroll
    for (int r = 0; r < 4; ++r)
      sShw[(quad * 4 + r) * 36 + tk * 16 + l16] = f2bf(c[r]);
  }

  // ---- Sw[q][j] = Qs·rp8w[j]; held in regs until barrier ----
  f32x4 swc[4];
  #pragma unroll
  for (int tj = 0; tj < 4; ++tj) {
    const u16* bp = uRPW + (tj * 16 + l16) * 72 + quad * 8;
    bf16x8 b0 = *(const bf16x8*)(bp);
    bf16x8 b1 = *(const bf16x8*)(bp + 32);
    f32x4 c; c[0] = 0.f; c[1] = 0.f; c[2] = 0.f; c[3] = 0.f;
    c = MFMA(qf[0], b0, c);
    c = MFMA(qf[1], b1, c);
    swc[tj] = c;
  }
  __syncthreads();   // all uRPH/uRPW reads complete before pw overwrites

  #pragma unroll
  for (int tj = 0; tj < 4; ++tj)
    #pragma unroll
    for (int r = 0; r < 4; ++r)
      pw[(quad * 4 + r) * 72 + tj * 16 + l16] = f2bf(swc[tj][r]);

  // gather rel_w[qw][kw] = Sw[q][qw-kw+31] (wave-private, in-order RAW)
  float rw[2][4];
  #pragma unroll
  for (int hi = 0; hi < 2; ++hi)
    #pragma unroll
    for (int r = 0; r < 4; ++r) {
      const int kw = hi * 16 + quad * 4 + r;
      rw[hi][r] = bf2f(pw[l16 * 72 + (qwb + l16 - kw + 31)]);
    }

  f32x4 oacc[4];
  #pragma unroll
  for (int nd = 0; nd < 4; ++nd) {
    oacc[nd][0] = 0.f; oacc[nd][1] = 0.f; oacc[nd][2] = 0.f; oacc[nd][3] = 0.f;
  }
  float lsum = 0.f;

  const u16* const Kfb = Kf + (((size_t)bh) << 16) + lane * 8;
  const u16* const Vfb = Vf + (((size_t)bh) << 16) + lane * 8;

  for (int kt = 0; kt < 16; ++kt) {
    const u16* Kp = Kfb + ((size_t)kt << 12);
    const u16* Vp = Vfb + ((size_t)kt << 12);
    float rh[2];
    {
      const unsigned int w2 =
          *(const unsigned int*)(sShw + l16 * 36 + (kt << 1));
      rh[0] = bf2f((u16)(w2 & 0xffffu));
      rh[1] = bf2f((u16)(w2 >> 16));
    }
    // S^T = K·Qs^T  (A = K frags, coalesced; B = Q regs)
    f32x4 sacc[4];
    #pragma unroll
    for (int mk = 0; mk < 4; ++mk) {
      bf16x8 kf0 = *(const bf16x8*)(Kp + ((mk * 2 + 0) << 9));
      bf16x8 kf1 = *(const bf16x8*)(Kp + ((mk * 2 + 1) << 9));
      f32x4 t4; t4[0] = 0.f; t4[1] = 0.f; t4[2] = 0.f; t4[3] = 0.f;
      t4 = MFMA(kf0, qf[0], t4);
      t4 = MFMA(kf1, qf[1], t4);
      sacc[mk] = t4;
    }
    // logit = add3 (log2 domain), exp2, pack pairs, store P (16 q x 64 key)
    #pragma unroll
    for (int mk = 0; mk < 4; ++mk) {
      const float rhv = rh[mk >> 1];
      const float* rwp = rw[mk & 1];
      float e0 = EXP2(sacc[mk][0] + rhv + rwp[0]);
      float e1 = EXP2(sacc[mk][1] + rhv + rwp[1]);
      float e2 = EXP2(sacc[mk][2] + rhv + rwp[2]);
      float e3 = EXP2(sacc[mk][3] + rhv + rwp[3]);
      lsum += (e0 + e1) + (e2 + e3);
      uint2 pk2; pk2.x = pk2bf(e0, e1); pk2.y = pk2bf(e2, e3);
      *(uint2*)(pw + l16 * 72 + mk * 16 + quad * 4) = pk2;
    }
    // O^T += V^T·P^T  (A = V frags, coalesced; B = P from LDS, same-wave)
    #pragma unroll
    for (int ks = 0; ks < 2; ++ks) {
      bf16x8 ap = *(const bf16x8*)(pw + l16 * 72 + ks * 32 + quad * 8);
      #pragma unroll
      for (int nd = 0; nd < 4; ++nd) {
        bf16x8 bv = *(const bf16x8*)(Vp + ((ks * 4 + nd) << 9));
        oacc[nd] = MFMA(bv, ap, oacc[nd]);
      }
    }
  }

  // softmax denominator: lane's column q = l16; fold quads
  lsum += __shfl_xor(lsum, 16);
  lsum += __shfl_xor(lsum, 32);

  const int b = bh / 12, head = bh - b * 12;
  const float linv = 1.0f / lsum;
  const size_t base =
      ((size_t)(b << 10) + qrow0 + l16) * 768 + head * 64 + quad * 4;
  #pragma unroll
  for (int nd = 0; nd < 4; ++nd) {
    s16x4 pk;
    #pragma unroll
    for (int r = 0; r < 4; ++r) pk[r] = (short)f2bf(oacc[nd][r] * linv);
    *(s16x4*)(Oa + base + nd * 16) = pk;
  }
}

// ---------------------------------------------------------------------------
extern "C" void kernel_launch(void* const* d_in, const int* in_sizes, int n_in,
                              void* d_out, int out_size, void* d_ws, size_t ws_size,
                              hipStream_t stream) {
  (void)in_sizes; (void)n_in; (void)out_size; (void)ws_size;
  const float* x      = (const float*)d_in[0];   // (8,32,32,768)
  const float* qkv_w  = (const float*)d_in[1];   // (2304,768)
  const float* qkv_b  = (const float*)d_in[2];   // (2304)
  const float* proj_w = (const float*)d_in[3];   // (768,768)
  const float* proj_b = (const float*)d_in[4];   // (768)
  const float* rph    = (const float*)d_in[5];   // (63,64)
  const float* rpw    = (const float*)d_in[6];   // (63,64)
  float* out = (float*)d_out;

  char* ws = (char*)d_ws;
  const size_t SZ = (size_t)96 * 1024 * 64;     // elems per plane (12 MB)
  u16* Qw  = (u16*)ws;                          // Qs [bh][n][c] bf16 (pre-scaled)
  u16* Kfw = Qw + SZ;                           // K  fragment-linear bf16
  u16* Vfw = Kfw + SZ;                          // V  fragment-linear bf16
  u16* Xb  = Vfw + SZ;                          // bf16 x; aliased as Oa after QKV GEMM
  u16* Oa  = Xb;                                //   (x dead once QKV GEMM completes)
  u16* QWb = Xb + SZ;                           // bf16 qkv_w (2304x768)
  u16* PWb = QWb + (size_t)2304 * 768;          // bf16 proj_w (768x768)  -> ~55 MB total

  cast_kernel<<<4224, 256, 0, stream>>>(x, qkv_w, proj_w, Xb, QWb, PWb);
  gemm_bt<1, 18><<<1152, 256, 0, stream>>>(Xb, QWb, qkv_b, Qw, Kfw, Vfw, 8192, 2304, 768);
  attn_kernel<<<1536, 256, 0, stream>>>(Qw, Kfw, Vfw, rph, rpw, Oa);
  gemm_bt<0, 6><<<384, 256, 0, stream>>>(Oa, PWb, proj_b, out, nullptr, nullptr, 8192, 768, 768);
}